// Round 1
// baseline (2058.506 us; speedup 1.0000x reference)
//
#include <hip/hip_runtime.h>

typedef short short8 __attribute__((ext_vector_type(8)));
typedef float f32x4 __attribute__((ext_vector_type(4)));
typedef unsigned short ushort_t;

#define VOCAB 30000
#define DW 512
#define HDIM 512
#define G3 1536
#define TT 50
#define BB 128
#define M_ROWS 6400   /* T*B */
#define NPAD 30208    /* 118*256 */
#define NT_LSE 118
#define BN_LSE 256

__device__ __forceinline__ float b2f(ushort_t u){ return __uint_as_float(((unsigned)u)<<16); }
__device__ __forceinline__ ushort_t f2b(float f){
    unsigned u = __float_as_uint(f);
    unsigned r = (u + 0x7fffu + ((u>>16)&1u)) >> 16;
    return (ushort_t)r;
}
__device__ __forceinline__ float sigf(float x){
    float e = __expf(-x);
    return __builtin_amdgcn_rcpf(1.0f + e);
}
__device__ __forceinline__ float tanh_(float x){
    return 2.0f*sigf(2.0f*x) - 1.0f;   // safe at +-inf
}

// ---------- setup kernels ----------
__global__ void k_cvt(const float* __restrict__ s, ushort_t* __restrict__ d, int n){
    int i = blockIdx.x*blockDim.x + threadIdx.x;
    if (i < n) d[i] = f2b(s[i]);
}
__global__ void k_zero_u(ushort_t* __restrict__ d, int n){
    int i = blockIdx.x*blockDim.x + threadIdx.x;
    if (i < n) d[i] = 0;
}
__global__ void k_gather(const float* __restrict__ emb, const int* __restrict__ idx,
                         ushort_t* __restrict__ x){
    int row = blockIdx.x;
    int v = idx[row];
    const float* src = emb + (size_t)v*DW;
    ushort_t* dst = x + (size_t)row*DW;
    for (int d = threadIdx.x; d < DW; d += blockDim.x) dst[d] = f2b(src[d]);
}
__global__ void k_biasg(const float* __restrict__ bi, const float* __restrict__ bh,
                        float* __restrict__ bg){
    int i = blockIdx.x*blockDim.x + threadIdx.x;
    if (i < G3) bg[i] = bi[i] + (i < 2*HDIM ? bh[i] : 0.0f);  // b_hh for n-gate stays inside r*( )
}
__global__ void k_zero_h(float* __restrict__ hf, ushort_t* __restrict__ hb, int n){
    int i = blockIdx.x*blockDim.x + threadIdx.x;
    if (i < n){ hf[i] = 0.0f; hb[i] = 0; }
}

// ---------- phase A: xg = x @ W_ih^T + (b_ih [+ b_hh for r,z]) , bf16 out ----------
// grid (1536/64, 6400/128), block 512 (8 waves, each 16 rows x 64 cols)
__global__ __launch_bounds__(512) void k_xg(const ushort_t* __restrict__ A,
        const ushort_t* __restrict__ Bw, const float* __restrict__ bg,
        ushort_t* __restrict__ xg){
    int lane = threadIdx.x & 63, wv = threadIdx.x >> 6;
    int lo = lane & 15, hi = lane >> 4;
    int n0 = blockIdx.x * 64;
    int m0 = blockIdx.y * 128 + wv * 16;
    f32x4 acc[4] = {};
    const ushort_t* Arow = A + (size_t)(m0 + lo)*DW;
    for (int kk = 0; kk < 16; ++kk){
        int k0 = kk*32 + hi*8;
        short8 a = *(const short8*)(Arow + k0);
        #pragma unroll
        for (int ni = 0; ni < 4; ++ni){
            short8 b = *(const short8*)(Bw + (size_t)(n0 + ni*16 + lo)*DW + k0);
            acc[ni] = __builtin_amdgcn_mfma_f32_16x16x32_bf16(a, b, acc[ni], 0, 0, 0);
        }
    }
    #pragma unroll
    for (int ni = 0; ni < 4; ++ni){
        int n = n0 + ni*16 + lo;
        float bb = bg[n];
        #pragma unroll
        for (int j = 0; j < 4; ++j){
            int m = m0 + hi*4 + j;
            xg[(size_t)m*G3 + n] = f2b(acc[ni][j] + bb);
        }
    }
}

// ---------- phase B: one GRU step ----------
// grid 32 (each WG owns 16 h-cols), block 512 (8 waves x 16 batch rows)
__global__ __launch_bounds__(512) void k_step(const ushort_t* __restrict__ hprev_b,
        const float* __restrict__ hprev_f, const ushort_t* __restrict__ Whh,
        const ushort_t* __restrict__ xg, const float* __restrict__ bh,
        float* __restrict__ hnext_f, ushort_t* __restrict__ hnext_b,
        ushort_t* __restrict__ outs, int t){
    int lane = threadIdx.x & 63, wv = threadIdx.x >> 6;
    int lo = lane & 15, hi = lane >> 4;
    int c16 = blockIdx.x * 16;   // h-col base owned by this WG
    int b0  = wv * 16;           // batch base for this wave
    f32x4 acc[3] = {};
    const ushort_t* Arow = hprev_b + (size_t)(b0 + lo)*HDIM;
    for (int kk = 0; kk < 16; ++kk){
        int k0 = kk*32 + hi*8;
        short8 a = *(const short8*)(Arow + k0);
        #pragma unroll
        for (int g = 0; g < 3; ++g){
            short8 b = *(const short8*)(Whh + (size_t)(g*HDIM + c16 + lo)*HDIM + k0);
            acc[g] = __builtin_amdgcn_mfma_f32_16x16x32_bf16(a, b, acc[g], 0, 0, 0);
        }
    }
    int c = c16 + lo;
    float bhn = bh[2*HDIM + c];
    const ushort_t* xgt = xg + (size_t)t*BB*G3;
    #pragma unroll
    for (int j = 0; j < 4; ++j){
        int bt = b0 + hi*4 + j;
        float xr = b2f(xgt[(size_t)bt*G3 + c]);
        float xz = b2f(xgt[(size_t)bt*G3 + HDIM + c]);
        float xn = b2f(xgt[(size_t)bt*G3 + 2*HDIM + c]);
        float r  = sigf(acc[0][j] + xr);
        float z  = sigf(acc[1][j] + xz);
        float n  = tanh_(xn + r*(acc[2][j] + bhn));
        float hold = hprev_f[(size_t)bt*HDIM + c];
        float hnew = (1.0f - z)*n + z*hold;
        hnext_f[(size_t)bt*HDIM + c] = hnew;
        ushort_t hb = f2b(hnew);
        hnext_b[(size_t)bt*HDIM + c] = hb;
        outs[((size_t)t*BB + bt)*HDIM + c] = hb;
    }
}

// ---------- phase C1: fused logits tile + per-row (max, sumexp) partials ----------
// grid (118, 50), block 256 (4 waves x 32 rows); BN=256 cols per WG
__global__ __launch_bounds__(256) void k_lse_partial(const ushort_t* __restrict__ A,
        const ushort_t* __restrict__ Wo, const float* __restrict__ bo,
        float* __restrict__ pmax, float* __restrict__ psum){
    int lane = threadIdx.x & 63, wv = threadIdx.x >> 6;
    int lo = lane & 15, hi = lane >> 4;
    int n0 = blockIdx.x * BN_LSE;
    int m0 = blockIdx.y * 128 + wv * 32;
    f32x4 acc[2][16] = {};
    const ushort_t* A0 = A + (size_t)(m0 + lo)*DW;
    const ushort_t* A1 = A + (size_t)(m0 + 16 + lo)*DW;
    for (int kk = 0; kk < 16; ++kk){
        int k0 = kk*32 + hi*8;
        short8 a0 = *(const short8*)(A0 + k0);
        short8 a1 = *(const short8*)(A1 + k0);
        #pragma unroll
        for (int ni = 0; ni < 16; ++ni){
            short8 b = *(const short8*)(Wo + (size_t)(n0 + ni*16 + lo)*DW + k0);
            acc[0][ni] = __builtin_amdgcn_mfma_f32_16x16x32_bf16(a0, b, acc[0][ni], 0, 0, 0);
            acc[1][ni] = __builtin_amdgcn_mfma_f32_16x16x32_bf16(a1, b, acc[1][ni], 0, 0, 0);
        }
    }
    float bov[16];
    bool valid[16];
    #pragma unroll
    for (int ni = 0; ni < 16; ++ni){
        int col = n0 + ni*16 + lo;
        valid[ni] = (col < VOCAB);
        bov[ni] = valid[ni] ? bo[col] : 0.0f;
    }
    #pragma unroll
    for (int mi = 0; mi < 2; ++mi){
        #pragma unroll
        for (int j = 0; j < 4; ++j){
            float mx = -1e30f;
            #pragma unroll
            for (int ni = 0; ni < 16; ++ni){
                float lv = valid[ni] ? (acc[mi][ni][j] + bov[ni]) : -1e30f;
                mx = fmaxf(mx, lv);
            }
            for (int d = 1; d < 16; d <<= 1) mx = fmaxf(mx, __shfl_xor(mx, d, 64));
            float s = 0.0f;
            #pragma unroll
            for (int ni = 0; ni < 16; ++ni){
                float lv = valid[ni] ? (acc[mi][ni][j] + bov[ni]) : -1e30f;
                s += __expf(lv - mx);
            }
            for (int d = 1; d < 16; d <<= 1) s += __shfl_xor(s, d, 64);
            if (lo == 0){
                int m = m0 + mi*16 + hi*4 + j;
                pmax[(size_t)blockIdx.x*M_ROWS + m] = mx;
                psum[(size_t)blockIdx.x*M_ROWS + m] = s;
            }
        }
    }
}

// ---------- phase C2: combine partials -> lse ----------
__global__ void k_comb(const float* __restrict__ pmax, const float* __restrict__ psum,
                       float* __restrict__ lse){
    int r = blockIdx.x*blockDim.x + threadIdx.x;
    if (r >= M_ROWS) return;
    float M = -1e30f;
    for (int t = 0; t < NT_LSE; ++t) M = fmaxf(M, pmax[(size_t)t*M_ROWS + r]);
    float S = 0.0f;
    for (int t = 0; t < NT_LSE; ++t) S += psum[(size_t)t*M_ROWS + r] * __expf(pmax[(size_t)t*M_ROWS + r] - M);
    lse[r] = M + __logf(S);
}

// ---------- phase C3: nll per row ----------
// grid 1600, block 256 (4 waves, one row each)
__global__ __launch_bounds__(256) void k_loss(const ushort_t* __restrict__ outs,
        const ushort_t* __restrict__ Wo, const float* __restrict__ bo,
        const float* __restrict__ lse, const int* __restrict__ tgt,
        float* __restrict__ out){
    int lane = threadIdx.x & 63, wv = threadIdx.x >> 6;
    int row = blockIdx.x*4 + wv;
    int tg = tgt[row];
    const ushort_t* a = outs + (size_t)row*HDIM + lane*8;
    const ushort_t* w = Wo + (size_t)tg*DW + lane*8;
    float s = 0.0f;
    #pragma unroll
    for (int j = 0; j < 8; ++j) s += b2f(a[j]) * b2f(w[j]);
    for (int d = 1; d < 64; d <<= 1) s += __shfl_xor(s, d, 64);
    if (lane == 0){
        float logit = s + bo[tg];
        out[row] = (tg != 0) ? (lse[row] - logit) : 0.0f;
    }
}

// ---------- phase C4: obj = sum(loss)/max(count,1) ----------
__global__ __launch_bounds__(1024) void k_obj(const float* __restrict__ loss,
        const int* __restrict__ tgt, float* __restrict__ out){
    __shared__ float ss[1024];
    __shared__ int   sc[1024];
    float s = 0.0f; int c = 0;
    for (int i = threadIdx.x; i < M_ROWS; i += 1024){
        s += loss[i];
        c += (tgt[i] != 0) ? 1 : 0;
    }
    ss[threadIdx.x] = s; sc[threadIdx.x] = c;
    __syncthreads();
    for (int d = 512; d > 0; d >>= 1){
        if (threadIdx.x < (unsigned)d){ ss[threadIdx.x] += ss[threadIdx.x+d]; sc[threadIdx.x] += sc[threadIdx.x+d]; }
        __syncthreads();
    }
    if (threadIdx.x == 0) out[M_ROWS] = ss[0] / (float)(sc[0] > 0 ? sc[0] : 1);
}

extern "C" void kernel_launch(void* const* d_in, const int* in_sizes, int n_in,
                              void* d_out, int out_size, void* d_ws, size_t ws_size,
                              hipStream_t stream) {
    const int*   review_input  = (const int*)d_in[2];
    const int*   review_target = (const int*)d_in[3];
    const float* word_emb = (const float*)d_in[4];
    const float* W_ih = (const float*)d_in[5];
    const float* W_hh = (const float*)d_in[6];
    const float* b_ih = (const float*)d_in[7];
    const float* b_hh = (const float*)d_in[8];
    const float* W_out = (const float*)d_in[9];
    const float* b_out = (const float*)d_in[10];
    float* out = (float*)d_out;
    (void)review_input; (void)n_in; (void)in_sizes; (void)out_size; (void)ws_size;

    char* ws = (char*)d_ws;
    size_t off = 0;
    auto alloc = [&](size_t bytes)->char*{
        char* p = ws + off;
        off = (off + bytes + 255) & ~(size_t)255;
        return p;
    };
    ushort_t* Wout_b = (ushort_t*)alloc((size_t)NPAD*DW*2);      // 30.9 MB (padded)
    ushort_t* Wih_b  = (ushort_t*)alloc((size_t)G3*DW*2);        // 1.6 MB
    ushort_t* Whh_b  = (ushort_t*)alloc((size_t)G3*HDIM*2);      // 1.6 MB
    ushort_t* xb     = (ushort_t*)alloc((size_t)M_ROWS*DW*2);    // 6.6 MB
    ushort_t* outs_b = (ushort_t*)alloc((size_t)M_ROWS*HDIM*2);  // 6.6 MB
    ushort_t* xg     = (ushort_t*)alloc((size_t)M_ROWS*G3*2);    // 19.7 MB
    float*    biasg  = (float*)alloc((size_t)G3*4);
    float*    h_f    = (float*)alloc((size_t)2*BB*HDIM*4);       // double buffered
    ushort_t* h_b    = (ushort_t*)alloc((size_t)2*BB*HDIM*2);
    float*    pmax   = (float*)alloc((size_t)NT_LSE*M_ROWS*4);   // 3.0 MB
    float*    psum   = (float*)alloc((size_t)NT_LSE*M_ROWS*4);   // 3.0 MB
    float*    lse    = (float*)alloc((size_t)M_ROWS*4);

    // setup / converts
    k_cvt<<<(G3*DW+255)/256, 256, 0, stream>>>(W_ih, Wih_b, G3*DW);
    k_cvt<<<(G3*HDIM+255)/256, 256, 0, stream>>>(W_hh, Whh_b, G3*HDIM);
    k_cvt<<<(VOCAB*DW+255)/256, 256, 0, stream>>>(W_out, Wout_b, VOCAB*DW);
    k_zero_u<<<((NPAD-VOCAB)*DW+255)/256, 256, 0, stream>>>(Wout_b + (size_t)VOCAB*DW, (NPAD-VOCAB)*DW);
    k_gather<<<M_ROWS, 256, 0, stream>>>(word_emb, review_input, xb);
    k_biasg<<<(G3+255)/256, 256, 0, stream>>>(b_ih, b_hh, biasg);
    k_zero_h<<<(BB*HDIM+255)/256, 256, 0, stream>>>(h_f, h_b, BB*HDIM);

    // phase A
    k_xg<<<dim3(G3/64, M_ROWS/128), 512, 0, stream>>>(xb, Wih_b, biasg, xg);

    // phase B: 50 sequential steps, double-buffered h
    for (int t = 0; t < TT; ++t){
        int cur = t & 1, nxt = cur ^ 1;
        k_step<<<32, 512, 0, stream>>>(h_b + (size_t)cur*BB*HDIM,
                                       h_f + (size_t)cur*BB*HDIM,
                                       Whh_b, xg, b_hh,
                                       h_f + (size_t)nxt*BB*HDIM,
                                       h_b + (size_t)nxt*BB*HDIM,
                                       outs_b, t);
    }

    // phase C
    k_lse_partial<<<dim3(NT_LSE, M_ROWS/128), 256, 0, stream>>>(outs_b, Wout_b, b_out, pmax, psum);
    k_comb<<<(M_ROWS+255)/256, 256, 0, stream>>>(pmax, psum, lse);
    k_loss<<<M_ROWS/4, 256, 0, stream>>>(outs_b, Wout_b, b_out, lse, review_target, out);
    k_obj<<<1, 1024, 0, stream>>>(out, review_target, out);
}

// Round 2
// 708.681 us; speedup vs baseline: 2.9047x; 2.9047x over previous
//
#include <hip/hip_runtime.h>

typedef short short8 __attribute__((ext_vector_type(8)));
typedef float f32x4 __attribute__((ext_vector_type(4)));
typedef unsigned short ushort_t;

#define VOCAB 30000
#define DW 512
#define HDIM 512
#define G3 1536
#define TT 50
#define BB 128
#define M_ROWS 6400   /* T*B */
#define NPAD 30208    /* 236*128 */
#define NT2 472       /* partial tiles: 236 blocks x 2 wave-cols */

__device__ __forceinline__ float b2f(ushort_t u){ return __uint_as_float(((unsigned)u)<<16); }
__device__ __forceinline__ ushort_t f2b(float f){
    unsigned u = __float_as_uint(f);
    unsigned r = (u + 0x7fffu + ((u>>16)&1u)) >> 16;
    return (ushort_t)r;
}
__device__ __forceinline__ float sigf(float x){
    float e = __expf(-x);
    return __builtin_amdgcn_rcpf(1.0f + e);
}
__device__ __forceinline__ float tanh_(float x){
    return 2.0f*sigf(2.0f*x) - 1.0f;   // safe at +-inf
}
__device__ __forceinline__ void gload16(const ushort_t* g, char* l){
    __builtin_amdgcn_global_load_lds((const __attribute__((address_space(1))) void*)g,
                                     (__attribute__((address_space(3))) void*)l, 16, 0, 0);
}

// ---------- setup kernels ----------
__global__ void k_cvt(const float* __restrict__ s, ushort_t* __restrict__ d, int n){
    int i = blockIdx.x*blockDim.x + threadIdx.x;
    if (i < n) d[i] = f2b(s[i]);
}
__global__ void k_zero_u(ushort_t* __restrict__ d, int n){
    int i = blockIdx.x*blockDim.x + threadIdx.x;
    if (i < n) d[i] = 0;
}
__global__ void k_gather(const float* __restrict__ emb, const int* __restrict__ idx,
                         ushort_t* __restrict__ x){
    int row = blockIdx.x;
    int v = idx[row];
    const float* src = emb + (size_t)v*DW;
    ushort_t* dst = x + (size_t)row*DW;
    for (int d = threadIdx.x; d < DW; d += blockDim.x) dst[d] = f2b(src[d]);
}
__global__ void k_biasg(const float* __restrict__ bi, const float* __restrict__ bh,
                        float* __restrict__ bg){
    int i = blockIdx.x*blockDim.x + threadIdx.x;
    if (i < G3) bg[i] = bi[i] + (i < 2*HDIM ? bh[i] : 0.0f);  // b_hh for n-gate stays inside r*( )
}
__global__ void k_zero_h(float* __restrict__ hf, ushort_t* __restrict__ hb, int n){
    int i = blockIdx.x*blockDim.x + threadIdx.x;
    if (i < n){ hf[i] = 0.0f; hb[i] = 0; }
}

// ---------- tiled bf16 GEMM (m97 structure): C128x128 = A[128xK] * B[128xK]^T ----------
// block 256 (4 waves, 2x2 wave grid, each wave 64x64 via 4x4 16x16x32 frags), BK=32
// MODE 0: write bf16 C (+bias) with row stride G3  (xg path)
// MODE 1: per-row (max, sumexp) partials over this WG's 128 cols -> pmax/psum  (LSE path)
template<int MODE>
__global__ __launch_bounds__(256) void k_gemm(const ushort_t* __restrict__ A,
        const ushort_t* __restrict__ Bw, const float* __restrict__ bias,
        ushort_t* __restrict__ Cout, float* __restrict__ pmax, float* __restrict__ psum){
    __shared__ ushort_t As[128*32];
    __shared__ ushort_t Bs[128*32];
    int lane = threadIdx.x & 63, wv = threadIdx.x >> 6;
    int lo = lane & 15, hi = lane >> 4;
    int wr = wv >> 1, wc = wv & 1;
    int n0 = blockIdx.x * 128;
    int m0 = blockIdx.y * 128;
    f32x4 acc[4][4] = {};
    // staging: wave wv stages rows [wv*32, wv*32+32) of each 128x32 tile (2 calls of 1KB)
    const ushort_t* gA = A  + (size_t)(m0 + wv*32 + (lane>>2))*DW + (lane&3)*8;
    const ushort_t* gB = Bw + (size_t)(n0 + wv*32 + (lane>>2))*DW + (lane&3)*8;
    char* lA = (char*)As + wv*2048;
    char* lB = (char*)Bs + wv*2048;
    for (int kt = 0; kt < 16; ++kt){
        __syncthreads();
        int k0 = kt*32;
        gload16(gA + k0,           lA);
        gload16(gA + 16*DW + k0,   lA + 1024);
        gload16(gB + k0,           lB);
        gload16(gB + 16*DW + k0,   lB + 1024);
        __syncthreads();
        short8 av[4], bv[4];
        #pragma unroll
        for (int mi = 0; mi < 4; ++mi)
            av[mi] = *(const short8*)&As[(wr*64 + mi*16 + lo)*32 + hi*8];
        #pragma unroll
        for (int ni = 0; ni < 4; ++ni)
            bv[ni] = *(const short8*)&Bs[(wc*64 + ni*16 + lo)*32 + hi*8];
        #pragma unroll
        for (int mi = 0; mi < 4; ++mi)
            #pragma unroll
            for (int ni = 0; ni < 4; ++ni)
                acc[mi][ni] = __builtin_amdgcn_mfma_f32_16x16x32_bf16(av[mi], bv[ni], acc[mi][ni], 0, 0, 0);
    }

    if (MODE == 0){
        #pragma unroll
        for (int ni = 0; ni < 4; ++ni){
            int n = n0 + wc*64 + ni*16 + lo;
            float bb = bias[n];
            #pragma unroll
            for (int mi = 0; mi < 4; ++mi){
                #pragma unroll
                for (int j = 0; j < 4; ++j){
                    int m = m0 + wr*64 + mi*16 + hi*4 + j;
                    Cout[(size_t)m*G3 + n] = f2b(acc[mi][ni][j] + bb);
                }
            }
        }
    } else {
        float bov[4];
        bool valid[4];
        #pragma unroll
        for (int ni = 0; ni < 4; ++ni){
            int col = n0 + wc*64 + ni*16 + lo;
            valid[ni] = (col < VOCAB);
            bov[ni] = valid[ni] ? bias[col] : 0.0f;
        }
        int tile = blockIdx.x*2 + wc;
        #pragma unroll
        for (int mi = 0; mi < 4; ++mi){
            #pragma unroll
            for (int j = 0; j < 4; ++j){
                float lv[4];
                #pragma unroll
                for (int ni = 0; ni < 4; ++ni)
                    lv[ni] = valid[ni] ? (acc[mi][ni][j] + bov[ni]) : -1e30f;
                float mx = fmaxf(fmaxf(lv[0], lv[1]), fmaxf(lv[2], lv[3]));
                for (int d = 1; d < 16; d <<= 1) mx = fmaxf(mx, __shfl_xor(mx, d, 64));
                float s = 0.0f;
                #pragma unroll
                for (int ni = 0; ni < 4; ++ni)
                    s += __expf(lv[ni] - mx);
                for (int d = 1; d < 16; d <<= 1) s += __shfl_xor(s, d, 64);
                if (lo == 0){
                    int m = m0 + wr*64 + mi*16 + hi*4 + j;
                    pmax[(size_t)tile*M_ROWS + m] = mx;
                    psum[(size_t)tile*M_ROWS + m] = s;
                }
            }
        }
    }
}

// ---------- one GRU step: grid (32 col-tiles, 8 batch-tiles), block 64 (1 wave) ----------
// wave computes 16 batch x 16 h-cols x 3 gates, then the elementwise update
__global__ __launch_bounds__(64) void k_step(const ushort_t* __restrict__ hprev_b,
        const float* __restrict__ hprev_f, const ushort_t* __restrict__ Whh,
        const ushort_t* __restrict__ xg, const float* __restrict__ bh,
        float* __restrict__ hnext_f, ushort_t* __restrict__ hnext_b,
        ushort_t* __restrict__ outs, int t){
    int lane = threadIdx.x;
    int lo = lane & 15, hi = lane >> 4;
    int c16 = blockIdx.x * 16;   // h-col base
    int b0  = blockIdx.y * 16;   // batch base
    f32x4 acc[3] = {};
    const ushort_t* Arow = hprev_b + (size_t)(b0 + lo)*HDIM;
    #pragma unroll
    for (int kk = 0; kk < 16; ++kk){
        int k0 = kk*32 + hi*8;
        short8 a = *(const short8*)(Arow + k0);
        #pragma unroll
        for (int g = 0; g < 3; ++g){
            short8 b = *(const short8*)(Whh + (size_t)(g*HDIM + c16 + lo)*HDIM + k0);
            acc[g] = __builtin_amdgcn_mfma_f32_16x16x32_bf16(a, b, acc[g], 0, 0, 0);
        }
    }
    int c = c16 + lo;
    float bhn = bh[2*HDIM + c];
    const ushort_t* xgt = xg + (size_t)t*BB*G3;
    #pragma unroll
    for (int j = 0; j < 4; ++j){
        int bt = b0 + hi*4 + j;
        float xr = b2f(xgt[(size_t)bt*G3 + c]);
        float xz = b2f(xgt[(size_t)bt*G3 + HDIM + c]);
        float xn = b2f(xgt[(size_t)bt*G3 + 2*HDIM + c]);
        float r  = sigf(acc[0][j] + xr);
        float z  = sigf(acc[1][j] + xz);
        float n  = tanh_(xn + r*(acc[2][j] + bhn));
        float hold = hprev_f[(size_t)bt*HDIM + c];
        float hnew = (1.0f - z)*n + z*hold;
        hnext_f[(size_t)bt*HDIM + c] = hnew;
        ushort_t hb = f2b(hnew);
        hnext_b[(size_t)bt*HDIM + c] = hb;
        outs[((size_t)t*BB + bt)*HDIM + c] = hb;
    }
}

// ---------- combine partials -> lse ----------
__global__ void k_comb(const float* __restrict__ pmax, const float* __restrict__ psum,
                       float* __restrict__ lse){
    int r = blockIdx.x*blockDim.x + threadIdx.x;
    if (r >= M_ROWS) return;
    float M = -1e30f;
    for (int t = 0; t < NT2; ++t) M = fmaxf(M, pmax[(size_t)t*M_ROWS + r]);
    float S = 0.0f;
    for (int t = 0; t < NT2; ++t) S += psum[(size_t)t*M_ROWS + r] * __expf(pmax[(size_t)t*M_ROWS + r] - M);
    lse[r] = M + __logf(S);
}

// ---------- nll per row ----------
__global__ __launch_bounds__(256) void k_loss(const ushort_t* __restrict__ outs,
        const ushort_t* __restrict__ Wo, const float* __restrict__ bo,
        const float* __restrict__ lse, const int* __restrict__ tgt,
        float* __restrict__ out){
    int lane = threadIdx.x & 63, wv = threadIdx.x >> 6;
    int row = blockIdx.x*4 + wv;
    int tg = tgt[row];
    const ushort_t* a = outs + (size_t)row*HDIM + lane*8;
    const ushort_t* w = Wo + (size_t)tg*DW + lane*8;
    float s = 0.0f;
    #pragma unroll
    for (int j = 0; j < 8; ++j) s += b2f(a[j]) * b2f(w[j]);
    for (int d = 1; d < 64; d <<= 1) s += __shfl_xor(s, d, 64);
    if (lane == 0){
        float logit = s + bo[tg];
        out[row] = (tg != 0) ? (lse[row] - logit) : 0.0f;
    }
}

// ---------- obj = sum(loss)/max(count,1) ----------
__global__ __launch_bounds__(1024) void k_obj(const float* __restrict__ loss,
        const int* __restrict__ tgt, float* __restrict__ out){
    __shared__ float ss[1024];
    __shared__ int   sc[1024];
    float s = 0.0f; int c = 0;
    for (int i = threadIdx.x; i < M_ROWS; i += 1024){
        s += loss[i];
        c += (tgt[i] != 0) ? 1 : 0;
    }
    ss[threadIdx.x] = s; sc[threadIdx.x] = c;
    __syncthreads();
    for (int d = 512; d > 0; d >>= 1){
        if (threadIdx.x < (unsigned)d){ ss[threadIdx.x] += ss[threadIdx.x+d]; sc[threadIdx.x] += sc[threadIdx.x+d]; }
        __syncthreads();
    }
    if (threadIdx.x == 0) out[M_ROWS] = ss[0] / (float)(sc[0] > 0 ? sc[0] : 1);
}

extern "C" void kernel_launch(void* const* d_in, const int* in_sizes, int n_in,
                              void* d_out, int out_size, void* d_ws, size_t ws_size,
                              hipStream_t stream) {
    const int*   review_input  = (const int*)d_in[2];
    const int*   review_target = (const int*)d_in[3];
    const float* word_emb = (const float*)d_in[4];
    const float* W_ih = (const float*)d_in[5];
    const float* W_hh = (const float*)d_in[6];
    const float* b_ih = (const float*)d_in[7];
    const float* b_hh = (const float*)d_in[8];
    const float* W_out = (const float*)d_in[9];
    const float* b_out = (const float*)d_in[10];
    float* out = (float*)d_out;
    (void)n_in; (void)in_sizes; (void)out_size; (void)ws_size;

    char* ws = (char*)d_ws;
    size_t off = 0;
    auto alloc = [&](size_t bytes)->char*{
        char* p = ws + off;
        off = (off + bytes + 255) & ~(size_t)255;
        return p;
    };
    ushort_t* Wout_b = (ushort_t*)alloc((size_t)NPAD*DW*2);      // 30.9 MB (padded to 30208 rows)
    ushort_t* Wih_b  = (ushort_t*)alloc((size_t)G3*DW*2);        // 1.6 MB
    ushort_t* Whh_b  = (ushort_t*)alloc((size_t)G3*HDIM*2);      // 1.6 MB
    ushort_t* outs_b = (ushort_t*)alloc((size_t)M_ROWS*HDIM*2);  // 6.6 MB (live through phase C)
    float*    biasg  = (float*)alloc((size_t)G3*4);
    float*    h_f    = (float*)alloc((size_t)2*BB*HDIM*4);       // double buffered
    ushort_t* h_b    = (ushort_t*)alloc((size_t)2*BB*HDIM*2);
    float*    lse    = (float*)alloc((size_t)M_ROWS*4);
    // xb (6.55MB) + xg (19.66MB) are dead by phase C -> pmax/psum (24.17MB) alias this span
    ushort_t* xb     = (ushort_t*)alloc((size_t)M_ROWS*DW*2);
    ushort_t* xg     = (ushort_t*)alloc((size_t)M_ROWS*G3*2);
    float*    pmax   = (float*)xb;
    float*    psum   = pmax + (size_t)NT2*M_ROWS;

    // setup / converts
    k_cvt<<<(G3*DW+255)/256, 256, 0, stream>>>(W_ih, Wih_b, G3*DW);
    k_cvt<<<(G3*HDIM+255)/256, 256, 0, stream>>>(W_hh, Whh_b, G3*HDIM);
    k_cvt<<<(VOCAB*DW+255)/256, 256, 0, stream>>>(W_out, Wout_b, VOCAB*DW);
    k_zero_u<<<((NPAD-VOCAB)*DW+255)/256, 256, 0, stream>>>(Wout_b + (size_t)VOCAB*DW, (NPAD-VOCAB)*DW);
    k_gather<<<M_ROWS, 256, 0, stream>>>(word_emb, review_input, xb);
    k_biasg<<<(G3+255)/256, 256, 0, stream>>>(b_ih, b_hh, biasg);
    k_zero_h<<<(BB*HDIM+255)/256, 256, 0, stream>>>(h_f, h_b, BB*HDIM);

    // phase A: xg = x @ W_ih^T + biasg   (tiled GEMM, MODE 0)
    k_gemm<0><<<dim3(G3/128, M_ROWS/128), 256, 0, stream>>>(xb, Wih_b, biasg, xg, nullptr, nullptr);

    // phase B: 50 sequential steps, double-buffered h
    for (int t = 0; t < TT; ++t){
        int cur = t & 1, nxt = cur ^ 1;
        k_step<<<dim3(HDIM/16, BB/16), 64, 0, stream>>>(h_b + (size_t)cur*BB*HDIM,
                                       h_f + (size_t)cur*BB*HDIM,
                                       Whh_b, xg, b_hh,
                                       h_f + (size_t)nxt*BB*HDIM,
                                       h_b + (size_t)nxt*BB*HDIM,
                                       outs_b, t);
    }

    // phase C: fused logits + LSE partials (tiled GEMM, MODE 1), combine, nll, obj
    k_gemm<1><<<dim3(NPAD/128, M_ROWS/128), 256, 0, stream>>>(outs_b, Wout_b, b_out, nullptr, pmax, psum);
    k_comb<<<(M_ROWS+255)/256, 256, 0, stream>>>(pmax, psum, lse);
    k_loss<<<M_ROWS/4, 256, 0, stream>>>(outs_b, Wout_b, b_out, lse, review_target, out);
    k_obj<<<1, 1024, 0, stream>>>(out, review_target, out);
}